// Round 2
// baseline (260.428 us; speedup 1.0000x reference)
//
#include <hip/hip_runtime.h>
#include <math.h>

#define BATCH 64
#define DIM   1024
#define ROWS_PER_BLOCK 4

// ---------------------------------------------------------------------------
// Stage 1: per-row stats + staging of scaled/centered vectors.
// One block per batch row. 256 threads x float4 = 1024 elems per input.
// wa[b,i] = (x1[b,i]-m1) / ((D-1)*std1*std2)   (full scale folded in)
// wb[b,j] = (x2[b,j]-m2)
// ---------------------------------------------------------------------------
__global__ __launch_bounds__(256) void dca_stats_kernel(
    const float* __restrict__ x1, const float* __restrict__ x2,
    float* __restrict__ wa, float* __restrict__ wb) {
    const int b = blockIdx.x;
    const int t = threadIdx.x;

    const float4 v1 = reinterpret_cast<const float4*>(x1 + b * DIM)[t];
    const float4 v2 = reinterpret_cast<const float4*>(x2 + b * DIM)[t];

    float s1 = v1.x + v1.y + v1.z + v1.w;
    float q1 = v1.x * v1.x + v1.y * v1.y + v1.z * v1.z + v1.w * v1.w;
    float s2 = v2.x + v2.y + v2.z + v2.w;
    float q2 = v2.x * v2.x + v2.y * v2.y + v2.z * v2.z + v2.w * v2.w;

    // wave-64 butterfly reduction
    #pragma unroll
    for (int off = 32; off > 0; off >>= 1) {
        s1 += __shfl_xor(s1, off);
        q1 += __shfl_xor(q1, off);
        s2 += __shfl_xor(s2, off);
        q2 += __shfl_xor(q2, off);
    }

    __shared__ float red[4][4];   // [wave][quantity]
    __shared__ float bc[3];       // m1, m2, scale
    const int wave = t >> 6;
    const int lane = t & 63;
    if (lane == 0) {
        red[wave][0] = s1; red[wave][1] = q1;
        red[wave][2] = s2; red[wave][3] = q2;
    }
    __syncthreads();
    if (t == 0) {
        float S1 = 0.f, Q1 = 0.f, S2 = 0.f, Q2 = 0.f;
        #pragma unroll
        for (int w = 0; w < 4; ++w) {
            S1 += red[w][0]; Q1 += red[w][1];
            S2 += red[w][2]; Q2 += red[w][3];
        }
        const float invD = 1.0f / (float)DIM;
        const float m1 = S1 * invD;
        const float m2 = S2 * invD;
        // unbiased variance: (sum(x^2) - D*m^2) / (D-1)
        float var1 = (Q1 - (float)DIM * m1 * m1) / (float)(DIM - 1);
        float var2 = (Q2 - (float)DIM * m2 * m2) / (float)(DIM - 1);
        var1 = fmaxf(var1, 0.0f);
        var2 = fmaxf(var2, 0.0f);
        const float scale = 1.0f / ((float)(DIM - 1) * sqrtf(var1) * sqrtf(var2));
        bc[0] = m1; bc[1] = m2; bc[2] = scale;
    }
    __syncthreads();
    const float m1 = bc[0], m2 = bc[1], sc = bc[2];

    float4 a4, b4;
    a4.x = (v1.x - m1) * sc; a4.y = (v1.y - m1) * sc;
    a4.z = (v1.z - m1) * sc; a4.w = (v1.w - m1) * sc;
    b4.x = v2.x - m2; b4.y = v2.y - m2;
    b4.z = v2.z - m2; b4.w = v2.w - m2;
    reinterpret_cast<float4*>(wa + b * DIM)[t] = a4;
    reinterpret_cast<float4*>(wb + b * DIM)[t] = b4;
}

// ---------------------------------------------------------------------------
// Stage 2: outer-product write. One block per 4 output rows (same b).
// Load the wb row fragment once, scale by 4 per-row a values, 4 stores.
// out[b,i,j] = wa[b,i] * wb[b,j], float4 coalesced stores.
// ---------------------------------------------------------------------------
__global__ __launch_bounds__(256) void dca_outer_kernel(
    const float* __restrict__ wa, const float* __restrict__ wb,
    float* __restrict__ out) {
    const int blk = blockIdx.x;                 // 0 .. BATCH*DIM/ROWS_PER_BLOCK-1
    const int row0 = blk * ROWS_PER_BLOCK;      // = b*DIM + i0 (i0 % 4 == 0)
    const int b = row0 >> 10;

    const float4 v = reinterpret_cast<const float4*>(wb + (b << 10))[threadIdx.x];

    #pragma unroll
    for (int r = 0; r < ROWS_PER_BLOCK; ++r) {
        const float a = wa[row0 + r];           // uniform per block -> s-load
        float4 o;
        o.x = a * v.x; o.y = a * v.y; o.z = a * v.z; o.w = a * v.w;
        reinterpret_cast<float4*>(out + ((size_t)(row0 + r) << 10))[threadIdx.x] = o;
    }
}

extern "C" void kernel_launch(void* const* d_in, const int* in_sizes, int n_in,
                              void* d_out, int out_size, void* d_ws, size_t ws_size,
                              hipStream_t stream) {
    const float* x1 = (const float*)d_in[0];
    const float* x2 = (const float*)d_in[1];
    float* out = (float*)d_out;

    float* wa = (float*)d_ws;                 // BATCH*DIM floats
    float* wb = wa + BATCH * DIM;             // BATCH*DIM floats  (512 KiB total)

    dca_stats_kernel<<<BATCH, 256, 0, stream>>>(x1, x2, wa, wb);
    dca_outer_kernel<<<(BATCH * DIM) / ROWS_PER_BLOCK, 256, 0, stream>>>(wa, wb, out);
}

// Round 4
// 258.142 us; speedup vs baseline: 1.0089x; 1.0089x over previous
//
#include <hip/hip_runtime.h>
#include <math.h>

#define BATCH 64
#define DIM   1024
#define ROWS_PER_BLOCK 8

// ---------------------------------------------------------------------------
// Fused DCA similarity kernel.
// out[b,i,j] = (x1[b,i]-m1) * (x2[b,j]-m2) / ((D-1)*std1*std2)
//
// One block per 8 output rows (all same batch b, since 1024 % 8 == 0).
// Each block:
//   1. loads x1[b,:] and x2[b,:] (4 KiB each, L1/L2-resident across the
//      128 blocks sharing b) and reduces sum/sumsq for both,
//   2. broadcasts m1, m2 and the folded scale 1/((D-1)*std1*std2),
//   3. streams 8 rows of out with coalesced float4 stores; each thread's
//      x2-centered fragment is exactly the v2 float4 it already loaded.
// The store stream (32 KiB/block, 256 MiB total) is the roofline term;
// the redundant per-block stats (~8 KiB cached reads + ~50 VALU ops)
// overlap under it.
// ---------------------------------------------------------------------------
__global__ __launch_bounds__(256) void dca_fused_kernel(
    const float* __restrict__ x1, const float* __restrict__ x2,
    float* __restrict__ out) {
    const int blk  = blockIdx.x;                 // 0 .. BATCH*DIM/8 - 1
    const int row0 = blk * ROWS_PER_BLOCK;       // global row = b*DIM + i0
    const int b    = row0 >> 10;
    const int i0   = row0 & (DIM - 1);
    const int t    = threadIdx.x;

    const float4 v1 = reinterpret_cast<const float4*>(x1 + b * DIM)[t];
    const float4 v2 = reinterpret_cast<const float4*>(x2 + b * DIM)[t];

    float s1 = v1.x + v1.y + v1.z + v1.w;
    float q1 = v1.x * v1.x + v1.y * v1.y + v1.z * v1.z + v1.w * v1.w;
    float s2 = v2.x + v2.y + v2.z + v2.w;
    float q2 = v2.x * v2.x + v2.y * v2.y + v2.z * v2.z + v2.w * v2.w;

    // wave-64 butterfly reduction
    #pragma unroll
    for (int off = 32; off > 0; off >>= 1) {
        s1 += __shfl_xor(s1, off);
        q1 += __shfl_xor(q1, off);
        s2 += __shfl_xor(s2, off);
        q2 += __shfl_xor(q2, off);
    }

    __shared__ float red[4][4];   // [wave][quantity]
    __shared__ float bc[3];       // m1, m2, scale
    const int wave = t >> 6;
    const int lane = t & 63;
    if (lane == 0) {
        red[wave][0] = s1; red[wave][1] = q1;
        red[wave][2] = s2; red[wave][3] = q2;
    }
    __syncthreads();
    if (t == 0) {
        float S1 = 0.f, Q1 = 0.f, S2 = 0.f, Q2 = 0.f;
        #pragma unroll
        for (int w = 0; w < 4; ++w) {
            S1 += red[w][0]; Q1 += red[w][1];
            S2 += red[w][2]; Q2 += red[w][3];
        }
        const float invD = 1.0f / (float)DIM;
        const float m1 = S1 * invD;
        const float m2 = S2 * invD;
        // unbiased variance: (sum(x^2) - D*m^2) / (D-1)
        float var1 = (Q1 - (float)DIM * m1 * m1) / (float)(DIM - 1);
        float var2 = (Q2 - (float)DIM * m2 * m2) / (float)(DIM - 1);
        var1 = fmaxf(var1, 0.0f);
        var2 = fmaxf(var2, 0.0f);
        const float scale = 1.0f / ((float)(DIM - 1) * sqrtf(var1) * sqrtf(var2));
        bc[0] = m1; bc[1] = m2; bc[2] = scale;
    }
    __syncthreads();
    const float m1 = bc[0], m2 = bc[1], sc = bc[2];

    // centered x2 fragment: exactly the 4 j-positions this thread stores
    float4 w;
    w.x = v2.x - m2; w.y = v2.y - m2; w.z = v2.z - m2; w.w = v2.w - m2;

    // 8 per-row scalars a_r = (x1[b,i0+r] - m1) * scale  (L1-hit broadcasts)
    const float* x1row = x1 + b * DIM + i0;
    float a[ROWS_PER_BLOCK];
    #pragma unroll
    for (int r = 0; r < ROWS_PER_BLOCK; ++r)
        a[r] = (x1row[r] - m1) * sc;

    #pragma unroll
    for (int r = 0; r < ROWS_PER_BLOCK; ++r) {
        float4 o;
        o.x = a[r] * w.x; o.y = a[r] * w.y; o.z = a[r] * w.z; o.w = a[r] * w.w;
        reinterpret_cast<float4*>(out + ((size_t)(row0 + r) << 10))[t] = o;
    }
}

extern "C" void kernel_launch(void* const* d_in, const int* in_sizes, int n_in,
                              void* d_out, int out_size, void* d_ws, size_t ws_size,
                              hipStream_t stream) {
    const float* x1 = (const float*)d_in[0];
    const float* x2 = (const float*)d_in[1];
    float* out = (float*)d_out;

    dca_fused_kernel<<<(BATCH * DIM) / ROWS_PER_BLOCK, 256, 0, stream>>>(x1, x2, out);
}